// Round 1
// baseline (95.047 us; speedup 1.0000x reference)
//
#include <hip/hip_runtime.h>
#include <math.h>

// Problem constants (B=2, Cin=128, H=W=64, heads=8, dk=dv=32, Cout=128, K=7)
constexpr int HW    = 4096;   // 64*64
constexpr int WIMG  = 64;
constexpr int CQK   = 256;    // heads*dk
constexpr int NPXB  = 2 * HW; // total pixels over batch

// ---------------------------------------------------------------------------
// Generic fp32 projection GEMM: out[b][oc][p] = sum_c Wm[oc][c]*in[b][c][p] + bias[oc]
// Tile: 64 oc x 64 px per block, 256 threads, 4x4 register blocking.
// grid.x = B*64 (one 64-px row tile per image row), grid.y = OC/64
// ---------------------------------------------------------------------------
__global__ __launch_bounds__(256) void proj_gemm(
    const float* __restrict__ in, const float* __restrict__ Wm,
    const float* __restrict__ bias, float* __restrict__ out,
    int Cin, int OC)
{
    int pxt = blockIdx.x;
    int b   = pxt >> 6;
    int px0 = (pxt & 63) * 64;
    int oc0 = blockIdx.y * 64;

    __shared__ float Wt[32][64];  // [cc][oc_local]
    __shared__ float Xt[32][64];  // [cc][px_local]

    int t  = threadIdx.x;
    int to = (t >> 4) * 4;   // oc sub-offset
    int tp = (t & 15) * 4;   // px sub-offset

    float acc[4][4] = {};

    for (int c0 = 0; c0 < Cin; c0 += 32) {
        // load W chunk: thread t -> ol = t>>2 (0..63), cb8 = (t&3)*8
        int ol  = t >> 2;
        int cb8 = (t & 3) * 8;
        const float* wp = Wm + (size_t)(oc0 + ol) * Cin + c0 + cb8;
        float wreg[8];
        #pragma unroll
        for (int i = 0; i < 8; ++i) wreg[i] = wp[i];

        // load X chunk: thread t -> cc = t>>3 (0..31), pb = (t&7)*8
        int cc = t >> 3;
        int pb = (t & 7) * 8;
        const float* xp = in + ((size_t)b * Cin + (c0 + cc)) * HW + px0 + pb;
        float4 a0 = *(const float4*)xp;
        float4 a1 = *(const float4*)(xp + 4);

        __syncthreads();  // previous compute done before overwrite
        #pragma unroll
        for (int i = 0; i < 8; ++i) Wt[cb8 + i][ol] = wreg[i];
        *(float4*)&Xt[cc][pb]     = a0;
        *(float4*)&Xt[cc][pb + 4] = a1;
        __syncthreads();

        #pragma unroll
        for (int k = 0; k < 32; ++k) {
            float4 w = *(const float4*)&Wt[k][to];
            float4 xv = *(const float4*)&Xt[k][tp];
            float wv[4] = {w.x, w.y, w.z, w.w};
            float xa[4] = {xv.x, xv.y, xv.z, xv.w};
            #pragma unroll
            for (int i = 0; i < 4; ++i)
                #pragma unroll
                for (int j = 0; j < 4; ++j)
                    acc[i][j] = fmaf(wv[i], xa[j], acc[i][j]);
        }
    }

    #pragma unroll
    for (int i = 0; i < 4; ++i) {
        float bv = bias[oc0 + to + i];
        float* op = out + ((size_t)b * OC + oc0 + to + i) * HW + px0 + tp;
        float4 r = make_float4(acc[i][0] + bv, acc[i][1] + bv,
                               acc[i][2] + bv, acc[i][3] + bv);
        *(float4*)op = r;
    }
}

// ---------------------------------------------------------------------------
// Windowed attention: one block per (b, head, 16x16 pixel tile).
// Stage 22x22 halo of K (float2 over d-pairs) in LDS, compute 49 logits per
// thread, in-thread softmax, restage V into same LDS, weighted sum.
// grid.x = B*HEADS*16
// ---------------------------------------------------------------------------
__global__ __launch_bounds__(256) void attn_win(
    const float* __restrict__ kb, const float* __restrict__ qb,
    const float* __restrict__ vb, float* __restrict__ ab)
{
    __shared__ float2 S[16][22][23];  // [d/2][row][col(+pad)]

    int id   = blockIdx.x;
    int tile = id & 15;
    int bh   = id >> 4;
    int h    = bh & 7;
    int b    = bh >> 3;
    int ty0  = (tile >> 2) * 16;
    int tx0  = (tile & 3) * 16;

    int t  = threadIdx.x;
    int px = t & 15, py = t >> 4;
    int gy = ty0 + py, gx = tx0 + px;

    const size_t base = ((size_t)b * CQK + h * 32) * HW;

    // ---- stage K halo ----
    for (int e = t; e < 16 * 22 * 22; e += 256) {
        int d2 = e / 484;
        int rm = e - d2 * 484;
        int r  = rm / 22;
        int c  = rm - r * 22;
        int yy = ty0 - 3 + r, xx = tx0 - 3 + c;
        float2 val = make_float2(0.f, 0.f);
        if (yy >= 0 && yy < 64 && xx >= 0 && xx < 64) {
            const float* p = kb + base + (size_t)(2 * d2) * HW + yy * WIMG + xx;
            val.x = p[0];
            val.y = p[HW];
        }
        S[d2][r][c] = val;
    }

    // ---- load q into registers ----
    float2 q[16];
    #pragma unroll
    for (int d2 = 0; d2 < 16; ++d2) {
        const float* p = qb + base + (size_t)(2 * d2) * HW + gy * WIMG + gx;
        q[d2] = make_float2(p[0], p[HW]);
    }
    __syncthreads();

    // ---- logits ----
    float lg[49];
    #pragma unroll
    for (int dy = 0; dy < 7; ++dy) {
        #pragma unroll
        for (int dx = 0; dx < 7; ++dx) {
            float acc = 0.f;
            #pragma unroll
            for (int d2 = 0; d2 < 16; ++d2) {
                float2 kv = S[d2][py + dy][px + dx];
                acc = fmaf(q[d2].x, kv.x, acc);
                acc = fmaf(q[d2].y, kv.y, acc);
            }
            lg[dy * 7 + dx] = acc * 0.17677669529663687f;  // 1/sqrt(32)
        }
    }

    // ---- softmax over 49 ----
    float m = lg[0];
    #pragma unroll
    for (int a = 1; a < 49; ++a) m = fmaxf(m, lg[a]);
    float s = 0.f;
    #pragma unroll
    for (int a = 0; a < 49; ++a) { lg[a] = __expf(lg[a] - m); s += lg[a]; }
    float inv = 1.f / s;
    #pragma unroll
    for (int a = 0; a < 49; ++a) lg[a] *= inv;

    __syncthreads();  // everyone done reading K

    // ---- stage V halo (reuse S) ----
    for (int e = t; e < 16 * 22 * 22; e += 256) {
        int d2 = e / 484;
        int rm = e - d2 * 484;
        int r  = rm / 22;
        int c  = rm - r * 22;
        int yy = ty0 - 3 + r, xx = tx0 - 3 + c;
        float2 val = make_float2(0.f, 0.f);
        if (yy >= 0 && yy < 64 && xx >= 0 && xx < 64) {
            const float* p = vb + base + (size_t)(2 * d2) * HW + yy * WIMG + xx;
            val.x = p[0];
            val.y = p[HW];
        }
        S[d2][r][c] = val;
    }
    __syncthreads();

    // ---- weighted sum over window ----
    float2 acc[16];
    #pragma unroll
    for (int d2 = 0; d2 < 16; ++d2) acc[d2] = make_float2(0.f, 0.f);
    #pragma unroll
    for (int dy = 0; dy < 7; ++dy) {
        #pragma unroll
        for (int dx = 0; dx < 7; ++dx) {
            float sc = lg[dy * 7 + dx];
            #pragma unroll
            for (int d2 = 0; d2 < 16; ++d2) {
                float2 vv = S[d2][py + dy][px + dx];
                acc[d2].x = fmaf(sc, vv.x, acc[d2].x);
                acc[d2].y = fmaf(sc, vv.y, acc[d2].y);
            }
        }
    }

    // ---- store attn (B, 256, HW), channel = h*32 + d ----
    #pragma unroll
    for (int d2 = 0; d2 < 16; ++d2) {
        ab[base + (size_t)(2 * d2) * HW + gy * WIMG + gx]     = acc[d2].x;
        ab[base + (size_t)(2 * d2 + 1) * HW + gy * WIMG + gx] = acc[d2].y;
    }
}

// ---------------------------------------------------------------------------
extern "C" void kernel_launch(void* const* d_in, const int* in_sizes, int n_in,
                              void* d_out, int out_size, void* d_ws, size_t ws_size,
                              hipStream_t stream) {
    const float* x  = (const float*)d_in[0];
    const float* Wk = (const float*)d_in[1];
    const float* bk = (const float*)d_in[2];
    const float* Wq = (const float*)d_in[3];
    const float* bq = (const float*)d_in[4];
    const float* Wv = (const float*)d_in[5];
    const float* bv = (const float*)d_in[6];
    const float* Wo = (const float*)d_in[7];
    const float* bo = (const float*)d_in[8];
    float* out = (float*)d_out;

    float* ws = (float*)d_ws;
    const size_t BUF = (size_t)2 * CQK * HW;  // 2,097,152 floats
    float* kbuf = ws;
    float* qbuf = ws + BUF;
    float* vbuf = ws + 2 * BUF;
    float* abuf = ws + 3 * BUF;

    dim3 blk(256);
    // q/k/v projections: Cin=128, OC=256
    proj_gemm<<<dim3(128, 4), blk, 0, stream>>>(x, Wk, bk, kbuf, 128, 256);
    proj_gemm<<<dim3(128, 4), blk, 0, stream>>>(x, Wq, bq, qbuf, 128, 256);
    proj_gemm<<<dim3(128, 4), blk, 0, stream>>>(x, Wv, bv, vbuf, 128, 256);
    // windowed attention
    attn_win<<<dim3(256), blk, 0, stream>>>(kbuf, qbuf, vbuf, abuf);
    // output projection: Cin=256, OC=128
    proj_gemm<<<dim3(128, 2), blk, 0, stream>>>(abuf, Wo, bo, out, 256, 128);
}

// Round 2
// 75.859 us; speedup vs baseline: 1.2529x; 1.2529x over previous
//
#include <hip/hip_runtime.h>
#include <math.h>

// Problem constants (B=2, Cin=128, H=W=64, heads=8, dk=dv=32, Cout=128, K=7)
constexpr int HW   = 4096;   // 64*64
constexpr int WIMG = 64;

// ---------------------------------------------------------------------------
// Fused QKV projection: out[b][c3][hw], c3 = 0..255 K, 256..511 Q, 512..767 V
// Tile: 64 oc x 64 px per block, 256 threads, 4x4 register blocking.
// grid.x = B*64, grid.y = 768/64 = 12
// ---------------------------------------------------------------------------
__global__ __launch_bounds__(256) void qkv_gemm(
    const float* __restrict__ x,
    const float* __restrict__ Wk, const float* __restrict__ bk,
    const float* __restrict__ Wq, const float* __restrict__ bq,
    const float* __restrict__ Wv, const float* __restrict__ bv,
    float* __restrict__ out)
{
    constexpr int Cin = 128;
    int pxt = blockIdx.x;
    int b   = pxt >> 6;
    int px0 = (pxt & 63) * 64;
    int oc3 = blockIdx.y * 64;          // 0..767
    int sel = oc3 >> 8;
    int ocl = oc3 & 255;                // row offset within the selected W
    const float* Wm   = sel == 0 ? Wk : sel == 1 ? Wq : Wv;
    const float* bias = sel == 0 ? bk : sel == 1 ? bq : bv;

    __shared__ float Wt[32][64];  // [cc][oc_local]
    __shared__ float Xt[32][64];  // [cc][px_local]

    int t  = threadIdx.x;
    int to = (t >> 4) * 4;
    int tp = (t & 15) * 4;

    float acc[4][4] = {};

    for (int c0 = 0; c0 < Cin; c0 += 32) {
        int ol  = t >> 2;
        int cb8 = (t & 3) * 8;
        const float* wp = Wm + (size_t)(ocl + ol) * Cin + c0 + cb8;
        float wreg[8];
        #pragma unroll
        for (int i = 0; i < 8; ++i) wreg[i] = wp[i];

        int cc = t >> 3;
        int pb = (t & 7) * 8;
        const float* xp = x + ((size_t)b * Cin + (c0 + cc)) * HW + px0 + pb;
        float4 a0 = *(const float4*)xp;
        float4 a1 = *(const float4*)(xp + 4);

        __syncthreads();
        #pragma unroll
        for (int i = 0; i < 8; ++i) Wt[cb8 + i][ol] = wreg[i];
        *(float4*)&Xt[cc][pb]     = a0;
        *(float4*)&Xt[cc][pb + 4] = a1;
        __syncthreads();

        #pragma unroll
        for (int k = 0; k < 32; ++k) {
            float4 w  = *(const float4*)&Wt[k][to];
            float4 xv = *(const float4*)&Xt[k][tp];
            float wv[4] = {w.x, w.y, w.z, w.w};
            float xa[4] = {xv.x, xv.y, xv.z, xv.w};
            #pragma unroll
            for (int i = 0; i < 4; ++i)
                #pragma unroll
                for (int j = 0; j < 4; ++j)
                    acc[i][j] = fmaf(wv[i], xa[j], acc[i][j]);
        }
    }

    #pragma unroll
    for (int i = 0; i < 4; ++i) {
        float bv_ = bias[ocl + to + i];
        float* op = out + ((size_t)b * 768 + oc3 + to + i) * HW + px0 + tp;
        *(float4*)op = make_float4(acc[i][0] + bv_, acc[i][1] + bv_,
                                   acc[i][2] + bv_, acc[i][3] + bv_);
    }
}

// ---------------------------------------------------------------------------
// Generic fp32 projection GEMM (final output layer): Cin=256, OC=128
// ---------------------------------------------------------------------------
__global__ __launch_bounds__(256) void proj_gemm(
    const float* __restrict__ in, const float* __restrict__ Wm,
    const float* __restrict__ bias, float* __restrict__ out,
    int Cin, int OC)
{
    int pxt = blockIdx.x;
    int b   = pxt >> 6;
    int px0 = (pxt & 63) * 64;
    int oc0 = blockIdx.y * 64;

    __shared__ float Wt[32][64];
    __shared__ float Xt[32][64];

    int t  = threadIdx.x;
    int to = (t >> 4) * 4;
    int tp = (t & 15) * 4;

    float acc[4][4] = {};

    for (int c0 = 0; c0 < Cin; c0 += 32) {
        int ol  = t >> 2;
        int cb8 = (t & 3) * 8;
        const float* wp = Wm + (size_t)(oc0 + ol) * Cin + c0 + cb8;
        float wreg[8];
        #pragma unroll
        for (int i = 0; i < 8; ++i) wreg[i] = wp[i];

        int cc = t >> 3;
        int pb = (t & 7) * 8;
        const float* xp = in + ((size_t)b * Cin + (c0 + cc)) * HW + px0 + pb;
        float4 a0 = *(const float4*)xp;
        float4 a1 = *(const float4*)(xp + 4);

        __syncthreads();
        #pragma unroll
        for (int i = 0; i < 8; ++i) Wt[cb8 + i][ol] = wreg[i];
        *(float4*)&Xt[cc][pb]     = a0;
        *(float4*)&Xt[cc][pb + 4] = a1;
        __syncthreads();

        #pragma unroll
        for (int k = 0; k < 32; ++k) {
            float4 w  = *(const float4*)&Wt[k][to];
            float4 xv = *(const float4*)&Xt[k][tp];
            float wv[4] = {w.x, w.y, w.z, w.w};
            float xa[4] = {xv.x, xv.y, xv.z, xv.w};
            #pragma unroll
            for (int i = 0; i < 4; ++i)
                #pragma unroll
                for (int j = 0; j < 4; ++j)
                    acc[i][j] = fmaf(wv[i], xa[j], acc[i][j]);
        }
    }

    #pragma unroll
    for (int i = 0; i < 4; ++i) {
        float bv = bias[oc0 + to + i];
        float* op = out + ((size_t)b * OC + oc0 + to + i) * HW + px0 + tp;
        *(float4*)op = make_float4(acc[i][0] + bv, acc[i][1] + bv,
                                   acc[i][2] + bv, acc[i][3] + bv);
    }
}

// ---------------------------------------------------------------------------
// Windowed attention, d-split version.
// One block = (b, head, 8x8 pixel tile). 256 threads: thread = (pixel, dg),
// dg = t&3 owns d-channels dg*8 .. dg*8+7. Logits quad-reduced via shfl_xor.
// Halo 14x14x32 floats staged in S[14][14][36] (row stride 144B = 9*16B).
// grid.x = B*heads*64 = 1024
// ---------------------------------------------------------------------------
__global__ __launch_bounds__(256) void attn_win(
    const float* __restrict__ qkv, float* __restrict__ ab)
{
    __shared__ __align__(16) float S[14][14][36];

    int id   = blockIdx.x;
    int b    = id >> 9;
    int h    = (id >> 6) & 7;
    int tile = id & 63;
    int ty0  = (tile >> 3) * 8;
    int tx0  = (tile & 7) * 8;

    int t   = threadIdx.x;
    int pix = t >> 2;
    int dg  = t & 3;
    int py  = pix >> 3, px = pix & 7;
    int gy  = ty0 + py, gx = tx0 + px;

    const float* kb = qkv + ((size_t)b * 768 + h * 32) * HW;         // K planes
    const float* qb = qkv + ((size_t)b * 768 + 256 + h * 32) * HW;   // Q planes
    const float* vb = qkv + ((size_t)b * 768 + 512 + h * 32) * HW;   // V planes

    // ---- stage K halo: 196 halo pixels x 8 float4-chunks of d ----
    for (int e = t; e < 1568; e += 256) {
        int d4 = e & 7;
        int ph = e >> 3;
        int y  = ph / 14;
        int xc = ph - y * 14;
        int yy = ty0 - 3 + y, xx = tx0 - 3 + xc;
        float4 v = make_float4(0.f, 0.f, 0.f, 0.f);
        if (yy >= 0 && yy < 64 && xx >= 0 && xx < 64) {
            const float* p = kb + (size_t)(d4 * 4) * HW + yy * WIMG + xx;
            v.x = p[0]; v.y = p[HW]; v.z = p[2 * HW]; v.w = p[3 * HW];
        }
        *(float4*)&S[y][xc][d4 * 4] = v;
    }

    // ---- q (8 channels of this thread's d-group) ----
    float q[8];
    {
        const float* qp = qb + (size_t)(dg * 8) * HW + gy * WIMG + gx;
        #pragma unroll
        for (int j = 0; j < 8; ++j) q[j] = qp[(size_t)j * HW];
    }
    __syncthreads();

    // ---- partial logits over this thread's 8 d-channels ----
    float lg[49];
    #pragma unroll
    for (int dy = 0; dy < 7; ++dy) {
        #pragma unroll
        for (int dx = 0; dx < 7; ++dx) {
            const float* sp = &S[py + dy][px + dx][dg * 8];
            float4 k0 = *(const float4*)sp;
            float4 k1 = *(const float4*)(sp + 4);
            float a = q[0] * k0.x;
            a = fmaf(q[1], k0.y, a);
            a = fmaf(q[2], k0.z, a);
            a = fmaf(q[3], k0.w, a);
            a = fmaf(q[4], k1.x, a);
            a = fmaf(q[5], k1.y, a);
            a = fmaf(q[6], k1.z, a);
            a = fmaf(q[7], k1.w, a);
            lg[dy * 7 + dx] = a;
        }
    }

    // ---- quad reduce (4 d-groups of one pixel sit in adjacent lanes) ----
    #pragma unroll
    for (int a = 0; a < 49; ++a) {
        lg[a] += __shfl_xor(lg[a], 1);
        lg[a] += __shfl_xor(lg[a], 2);
    }

    // ---- softmax over 49 (every thread of the quad has identical sums) ----
    constexpr float scale = 0.17677669529663687f;  // 1/sqrt(32)
    float m = lg[0];
    #pragma unroll
    for (int a = 1; a < 49; ++a) m = fmaxf(m, lg[a]);
    float s = 0.f;
    #pragma unroll
    for (int a = 0; a < 49; ++a) {
        lg[a] = __expf((lg[a] - m) * scale);
        s += lg[a];
    }
    float inv = 1.f / s;

    __syncthreads();  // all logits reads of K done

    // ---- stage V halo (reuse S) ----
    for (int e = t; e < 1568; e += 256) {
        int d4 = e & 7;
        int ph = e >> 3;
        int y  = ph / 14;
        int xc = ph - y * 14;
        int yy = ty0 - 3 + y, xx = tx0 - 3 + xc;
        float4 v = make_float4(0.f, 0.f, 0.f, 0.f);
        if (yy >= 0 && yy < 64 && xx >= 0 && xx < 64) {
            const float* p = vb + (size_t)(d4 * 4) * HW + yy * WIMG + xx;
            v.x = p[0]; v.y = p[HW]; v.z = p[2 * HW]; v.w = p[3 * HW];
        }
        *(float4*)&S[y][xc][d4 * 4] = v;
    }
    __syncthreads();

    // ---- weighted sum over window for this thread's 8 d-channels ----
    float acc[8] = {};
    #pragma unroll
    for (int dy = 0; dy < 7; ++dy) {
        #pragma unroll
        for (int dx = 0; dx < 7; ++dx) {
            float w = lg[dy * 7 + dx] * inv;
            const float* sp = &S[py + dy][px + dx][dg * 8];
            float4 v0 = *(const float4*)sp;
            float4 v1 = *(const float4*)(sp + 4);
            acc[0] = fmaf(w, v0.x, acc[0]);
            acc[1] = fmaf(w, v0.y, acc[1]);
            acc[2] = fmaf(w, v0.z, acc[2]);
            acc[3] = fmaf(w, v0.w, acc[3]);
            acc[4] = fmaf(w, v1.x, acc[4]);
            acc[5] = fmaf(w, v1.y, acc[5]);
            acc[6] = fmaf(w, v1.z, acc[6]);
            acc[7] = fmaf(w, v1.w, acc[7]);
        }
    }

    // ---- store attn: [b][256][hw], channel = h*32 + dg*8 + j ----
    float* op = ab + ((size_t)b * 256 + h * 32 + dg * 8) * HW + gy * WIMG + gx;
    #pragma unroll
    for (int j = 0; j < 8; ++j) op[(size_t)j * HW] = acc[j];
}

// ---------------------------------------------------------------------------
extern "C" void kernel_launch(void* const* d_in, const int* in_sizes, int n_in,
                              void* d_out, int out_size, void* d_ws, size_t ws_size,
                              hipStream_t stream) {
    const float* x  = (const float*)d_in[0];
    const float* Wk = (const float*)d_in[1];
    const float* bk = (const float*)d_in[2];
    const float* Wq = (const float*)d_in[3];
    const float* bq = (const float*)d_in[4];
    const float* Wv = (const float*)d_in[5];
    const float* bv = (const float*)d_in[6];
    const float* Wo = (const float*)d_in[7];
    const float* bo = (const float*)d_in[8];
    float* out = (float*)d_out;

    float* ws = (float*)d_ws;
    float* qkv  = ws;                                   // [2][768][4096]
    float* abuf = ws + (size_t)2 * 768 * HW;            // [2][256][4096]

    dim3 blk(256);
    qkv_gemm<<<dim3(128, 12), blk, 0, stream>>>(x, Wk, bk, Wq, bq, Wv, bv, qkv);
    attn_win<<<dim3(1024), blk, 0, stream>>>(qkv, abuf);
    proj_gemm<<<dim3(128, 2), blk, 0, stream>>>(abuf, Wo, bo, out, 256, 128);
}